// Round 5
// baseline (1987.025 us; speedup 1.0000x reference)
//
#include <hip/hip_runtime.h>

#define INV_SQRT2f 0.70710678118654752440f

// Analysis filters (compile-time). Synthesis tap f[k] = AF[9-k] (time reversal).
// Polyphase synthesis: out[2q+p] = sum_{j=0..4} AF[9-(2j+p)] * x[(q+2-j) mod Nin]
constexpr float FARv[2][2][10] = {
  {{0.0f, -0.08838834764832f, 0.08838834764832f, 0.69587998903400f, 0.69587998903400f,
    0.08838834764832f, -0.08838834764832f, 0.01122679215254f, 0.01122679215254f, 0.0f},
   {0.0f, -0.01122679215254f, 0.01122679215254f, 0.08838834764832f, 0.08838834764832f,
    -0.69587998903400f, 0.69587998903400f, -0.08838834764832f, -0.08838834764832f, 0.0f}},
  {{0.01122679215254f, 0.01122679215254f, -0.08838834764832f, 0.08838834764832f, 0.69587998903400f,
    0.69587998903400f, 0.08838834764832f, -0.08838834764832f, 0.0f, 0.0f},
   {0.0f, 0.0f, -0.08838834764832f, -0.08838834764832f, 0.69587998903400f,
    -0.69587998903400f, 0.08838834764832f, 0.08838834764832f, 0.01122679215254f, -0.01122679215254f}}
};
constexpr float DUALv[2][2][10] = {
  {{0.03516384f, 0.0f, -0.08832942f, 0.23389032f, 0.76027237f,
    0.58751830f, 0.0f, -0.11430184f, 0.0f, 0.0f},
   {0.0f, 0.0f, -0.11430184f, 0.0f, 0.58751830f,
    -0.76027237f, 0.23389032f, 0.08832942f, 0.0f, -0.03516384f}},
  {{0.0f, 0.0f, -0.11430184f, 0.0f, 0.58751830f,
    0.76027237f, 0.23389032f, -0.08832942f, 0.0f, 0.03516384f},
   {-0.03516384f, 0.0f, 0.08832942f, 0.23389032f, -0.76027237f,
    0.58751830f, 0.0f, -0.11430184f, 0.0f, 0.0f}}
};

__host__ __device__ constexpr float tap(bool farq, int t, int lh, int k) {
  return (k < 0 || k > 9) ? 0.0f : (farq ? FARv[t][lh][k] : DUALv[t][lh][k]);
}

// ---- async staging of one 12x12x16 halo plane (576 float4) via global_load_lds.
// Zero result-VGPRs: HW DMA writes LDS directly. LDS dest is linear in lane
// order (wave-uniform base + lane*16) -- required by the instruction.
template<int NSZ>
__device__ __forceinline__ void stage_async(const float* __restrict__ src,
                                            float* __restrict__ dst,
                                            int ih0, int iw0, int tid) {
  #pragma unroll
  for (int it = 0; it < 3; ++it) {
    if (it < 2 || tid < 64) {            // wave-uniform guard (576 = 2*256 + 64)
      int e = tid + (it << 8);           // float4 index within plane
      int r = e / 48;                    // row (12 cols x 16 ch = 48 float4/row)
      int cc = e - r * 48;
      int gr = (ih0 + r - 2) & (NSZ - 1);
      int gc = (iw0 + (cc >> 2) - 2) & (NSZ - 1);
      const float* g = src + (((size_t)gr * NSZ + gc) << 4) + ((cc & 3) << 2);
      __builtin_amdgcn_global_load_lds(
          (const __attribute__((address_space(1))) void*)g,
          (__attribute__((address_space(3))) void*)(dst + (e << 2)),
          16, 0, 0);
    }
  }
}

// ---- per-quadrant synthesis from 7 RAW planes ----
// plane0 = lo/mid; planes1-3 = A0,A1,A2; planes4-6 = B0,B1,B2.
// Mix (A +/- B)*inv_sqrt2 folded into col taps:
//   lv += fl[j]*LO + fhc[j]*A0 +/- fhc[j]*B0
//   hv += flc[j]*A1 +/- flc[j]*B1 + fhc[j]*A2 +/- fhc[j]*B2
// Row pass gathered in registers (static indices after unroll).
template<bool FARQ, int M, int N, bool NEG>
__device__ __forceinline__ void synth7(const float* __restrict__ sIn, int s, int c,
                                       float (&acc)[16]) {
  const int pw = s & 1, qw = s >> 1;
  float fl[5], flc[5], fhc[5];
  #pragma unroll
  for (int j = 0; j < 5; ++j) {
    const float a  = pw ? tap(FARQ, N, 0, 8 - 2 * j) : tap(FARQ, N, 0, 9 - 2 * j);
    const float bb = pw ? tap(FARQ, N, 1, 8 - 2 * j) : tap(FARQ, N, 1, 9 - 2 * j);
    fl[j] = a;
    flc[j] = a * INV_SQRT2f;
    fhc[j] = bb * INV_SQRT2f;
  }
  float lo2[12], h2[12];
  const float* base = sIn + c;
  #pragma unroll
  for (int r = 0; r < 12; ++r) {
    const int rb = r * 192;
    float lv = 0.f, hv = 0.f;
    #pragma unroll
    for (int j = 0; j < 5; ++j) {
      const int o = rb + ((qw + 4 - j) << 4);
      const float LO = base[o];
      const float A0 = base[1 * 2304 + o];
      const float A1 = base[2 * 2304 + o];
      const float A2 = base[3 * 2304 + o];
      const float B0 = base[4 * 2304 + o];
      const float B1 = base[5 * 2304 + o];
      const float B2 = base[6 * 2304 + o];
      lv = fmaf(fl[j], LO, lv);
      lv = fmaf(fhc[j], A0, lv);
      lv = fmaf(fhc[j], NEG ? -B0 : B0, lv);
      hv = fmaf(flc[j], A1, hv);
      hv = fmaf(flc[j], NEG ? -B1 : B1, hv);
      hv = fmaf(fhc[j], A2, hv);
      hv = fmaf(fhc[j], NEG ? -B2 : B2, hv);
    }
    lo2[r] = lv; h2[r] = hv;
    __builtin_amdgcn_sched_barrier(0);   // bound ds_read hoisting window
  }
  #pragma unroll
  for (int nh = 0; nh < 16; ++nh) {
    const int ph = nh & 1, qh = nh >> 1;
    float v = 0.f;
    #pragma unroll
    for (int j = 0; j < 5; ++j) {
      v += tap(FARQ, M, 0, 9 - (2 * j + ph)) * lo2[qh + 4 - j]
         + tap(FARQ, M, 1, 9 - (2 * j + ph)) * h2[qh + 4 - j];
    }
    acc[nh] += v;
  }
}

// ---------------- Stage A: q-shift (128 -> 256); one quadrant-PAIR per block ----------------
// Pair P shares j1=P: quadrants (0,P) [sign +] and (1,1-P) [sign -] read the
// same w2 planes; only the lo plane is restaged between the two synths.
template<int P>
__device__ __forceinline__ void qshift_pair(const float* __restrict__ w2,
                                            const float* __restrict__ loT,
                                            float* __restrict__ mid,
                                            float* __restrict__ sIn,
                                            int b, int th, int tw, int tid) {
  const int c = tid & 15, s = tid >> 4;
  const int ih0 = th * 8, iw0 = tw * 8;
  const size_t plane = (size_t)128 * 128 * 16;
  const size_t mplane = (size_t)256 * 256 * 16;

  #pragma unroll
  for (int o = 0; o < 3; ++o) {
    stage_async<128>(w2 + ((size_t)((0 * 2 + P) * 3 + o) * 4 + b) * plane,
                     sIn + (1 + o) * 2304, ih0, iw0, tid);
    stage_async<128>(w2 + ((size_t)((1 * 2 + (1 - P)) * 3 + o) * 4 + b) * plane,
                     sIn + (4 + o) * 2304, ih0, iw0, tid);
  }
  stage_async<128>(loT + ((size_t)(0 * 2 + P) * 4 + b) * plane, sIn, ih0, iw0, tid);
  __syncthreads();
  {
    float acc[16];
    #pragma unroll
    for (int i = 0; i < 16; ++i) acc[i] = 0.f;
    synth7<false, 0, P, false>(sIn, s, c, acc);
    float* outQ = mid + ((size_t)P * 4 + b) * mplane;
    #pragma unroll
    for (int nh = 0; nh < 16; ++nh)
      outQ[(((size_t)(ih0 * 2 + nh)) * 256 + (size_t)(iw0 * 2 + s)) * 16 + c] = acc[nh];
  }
  __syncthreads();
  stage_async<128>(loT + ((size_t)(1 * 2 + (1 - P)) * 4 + b) * plane, sIn, ih0, iw0, tid);
  __syncthreads();
  {
    float acc[16];
    #pragma unroll
    for (int i = 0; i < 16; ++i) acc[i] = 0.f;
    synth7<false, 1, 1 - P, true>(sIn, s, c, acc);
    float* outQ = mid + ((size_t)(3 - P) * 4 + b) * mplane;
    #pragma unroll
    for (int nh = 0; nh < 16; ++nh)
      outQ[(((size_t)(ih0 * 2 + nh)) * 256 + (size_t)(iw0 * 2 + s)) * 16 + c] = acc[nh];
  }
}

__global__ __launch_bounds__(256) void qshift_kernel(
    const float* __restrict__ w2, const float* __restrict__ loT, float* __restrict__ mid) {
  __shared__ __align__(16) float sIn[7 * 2304];
  const int tid = threadIdx.x;
  const int tw = blockIdx.x, th = blockIdx.y;
  const int b = blockIdx.z & 3, p = blockIdx.z >> 2;
  if (p == 0) qshift_pair<0>(w2, loT, mid, sIn, b, th, tw, tid);
  else        qshift_pair<1>(w2, loT, mid, sIn, b, th, tw, tid);
}

// ---------------- Stage B: Farras (256 -> 512); both pairs, sum all 4 quadrants ----------------
__global__ __launch_bounds__(256) void farras_kernel(
    const float* __restrict__ w1, const float* __restrict__ mid, float* __restrict__ out) {
  __shared__ __align__(16) float sIn[7 * 2304];
  const int tid = threadIdx.x;
  const int c = tid & 15, s = tid >> 4;
  const int tw = blockIdx.x, th = blockIdx.y, b = blockIdx.z;
  const int ih0 = th * 8, iw0 = tw * 8;
  const size_t plane = (size_t)256 * 256 * 16;

  float acc[16];
  #pragma unroll
  for (int i = 0; i < 16; ++i) acc[i] = 0.f;

  // ---- pair 0 (j1=0): quadrant (0,0) with +, quadrant (1,1) with - ----
  #pragma unroll
  for (int o = 0; o < 3; ++o) {
    stage_async<256>(w1 + ((size_t)((0 * 2 + 0) * 3 + o) * 4 + b) * plane,
                     sIn + (1 + o) * 2304, ih0, iw0, tid);
    stage_async<256>(w1 + ((size_t)((1 * 2 + 1) * 3 + o) * 4 + b) * plane,
                     sIn + (4 + o) * 2304, ih0, iw0, tid);
  }
  stage_async<256>(mid + ((size_t)0 * 4 + b) * plane, sIn, ih0, iw0, tid);
  __syncthreads();
  synth7<true, 0, 0, false>(sIn, s, c, acc);
  __syncthreads();
  stage_async<256>(mid + ((size_t)3 * 4 + b) * plane, sIn, ih0, iw0, tid);
  __syncthreads();
  synth7<true, 1, 1, true>(sIn, s, c, acc);
  __syncthreads();

  // ---- pair 1 (j1=1): quadrant (0,1) with +, quadrant (1,0) with - ----
  #pragma unroll
  for (int o = 0; o < 3; ++o) {
    stage_async<256>(w1 + ((size_t)((0 * 2 + 1) * 3 + o) * 4 + b) * plane,
                     sIn + (1 + o) * 2304, ih0, iw0, tid);
    stage_async<256>(w1 + ((size_t)((1 * 2 + 0) * 3 + o) * 4 + b) * plane,
                     sIn + (4 + o) * 2304, ih0, iw0, tid);
  }
  stage_async<256>(mid + ((size_t)1 * 4 + b) * plane, sIn, ih0, iw0, tid);
  __syncthreads();
  synth7<true, 0, 1, false>(sIn, s, c, acc);
  __syncthreads();
  stage_async<256>(mid + ((size_t)2 * 4 + b) * plane, sIn, ih0, iw0, tid);
  __syncthreads();
  synth7<true, 1, 0, true>(sIn, s, c, acc);

  #pragma unroll
  for (int nh = 0; nh < 16; ++nh) {
    out[(((size_t)b * 512 + (ih0 * 2 + nh)) * 512 + (size_t)(iw0 * 2 + s)) * 16 + c] =
        acc[nh] * 0.5f;
  }
}

extern "C" void kernel_launch(void* const* d_in, const int* in_sizes, int n_in,
                              void* d_out, int out_size, void* d_ws, size_t ws_size,
                              hipStream_t stream) {
  const float* w1 = (const float*)d_in[0];   // [2,2,3,4,256,256,16]
  const float* w2 = (const float*)d_in[1];   // [2,2,3,4,128,128,16]
  const float* lo = (const float*)d_in[2];   // [2,2,4,128,128,16]
  float* out = (float*)d_out;                // [4,512,512,16]
  float* mid = (float*)d_ws;                 // [4 quadrants][4][256][256][16] = 64 MiB

  qshift_kernel<<<dim3(16, 16, 8), 256, 0, stream>>>(w2, lo, mid);
  farras_kernel<<<dim3(32, 32, 4), 256, 0, stream>>>(w1, mid, out);
}

// Round 6
// 276.446 us; speedup vs baseline: 7.1878x; 7.1878x over previous
//
#include <hip/hip_runtime.h>

#define INV_SQRT2f 0.70710678118654752440f

// Analysis filters; synthesis filter f[k] = AF[9-k] (time reversal).
// Polyphase synthesis: out[2q+p] = sum_{j=0..4} AF[9-(2j+p)] * x[(q+2-j) mod Nin]
__constant__ float c_FAR[2][2][10] = {
  {{0.0f, -0.08838834764832f, 0.08838834764832f, 0.69587998903400f, 0.69587998903400f,
    0.08838834764832f, -0.08838834764832f, 0.01122679215254f, 0.01122679215254f, 0.0f},
   {0.0f, -0.01122679215254f, 0.01122679215254f, 0.08838834764832f, 0.08838834764832f,
    -0.69587998903400f, 0.69587998903400f, -0.08838834764832f, -0.08838834764832f, 0.0f}},
  {{0.01122679215254f, 0.01122679215254f, -0.08838834764832f, 0.08838834764832f, 0.69587998903400f,
    0.69587998903400f, 0.08838834764832f, -0.08838834764832f, 0.0f, 0.0f},
   {0.0f, 0.0f, -0.08838834764832f, -0.08838834764832f, 0.69587998903400f,
    -0.69587998903400f, 0.08838834764832f, 0.08838834764832f, 0.01122679215254f, -0.01122679215254f}}
};
__constant__ float c_DUAL[2][2][10] = {
  {{0.03516384f, 0.0f, -0.08832942f, 0.23389032f, 0.76027237f,
    0.58751830f, 0.0f, -0.11430184f, 0.0f, 0.0f},
   {0.0f, 0.0f, -0.11430184f, 0.0f, 0.58751830f,
    -0.76027237f, 0.23389032f, 0.08832942f, 0.0f, -0.03516384f}},
  {{0.0f, 0.0f, -0.11430184f, 0.0f, 0.58751830f,
    0.76027237f, 0.23389032f, -0.08832942f, 0.0f, 0.03516384f},
   {-0.03516384f, 0.0f, 0.08832942f, 0.23389032f, -0.76027237f,
    0.58751830f, 0.0f, -0.11430184f, 0.0f, 0.0f}}
};

// ---- staging: 12x12 spatial halo tile x 16 ch = 576 float4, 256 threads ----
template<int NSZ>
__device__ __forceinline__ void stage_copy(const float* __restrict__ src, float* __restrict__ dst,
                                           int ih0, int iw0, int tid) {
  #pragma unroll
  for (int it = 0; it < 3; ++it) {
    int e = tid + (it << 8);
    if (it < 2 || e < 576) {
      int r = e / 48;
      int cc = e - r * 48;
      int gr = (ih0 + r - 2) & (NSZ - 1);
      int gc = (iw0 + (cc >> 2) - 2) & (NSZ - 1);
      float4 v = *reinterpret_cast<const float4*>(src + (((size_t)gr * NSZ + gc) << 4) + ((cc & 3) << 2));
      *reinterpret_cast<float4*>(dst + (e << 2)) = v;
    }
  }
}

template<int NSZ>
__device__ __forceinline__ void stage_mix(const float* __restrict__ A, const float* __restrict__ B,
                                          float sgn, float* __restrict__ dst,
                                          int ih0, int iw0, int tid) {
  #pragma unroll
  for (int it = 0; it < 3; ++it) {
    int e = tid + (it << 8);
    if (it < 2 || e < 576) {
      int r = e / 48;
      int cc = e - r * 48;
      int gr = (ih0 + r - 2) & (NSZ - 1);
      int gc = (iw0 + (cc >> 2) - 2) & (NSZ - 1);
      size_t off = (((size_t)gr * NSZ + gc) << 4) + ((cc & 3) << 2);
      float4 a = *reinterpret_cast<const float4*>(A + off);
      float4 b = *reinterpret_cast<const float4*>(B + off);
      float4 v;
      v.x = (a.x + sgn * b.x) * INV_SQRT2f;
      v.y = (a.y + sgn * b.y) * INV_SQRT2f;
      v.z = (a.z + sgn * b.z) * INV_SQRT2f;
      v.w = (a.w + sgn * b.w) * INV_SQRT2f;
      *reinterpret_cast<float4*>(dst + (e << 2)) = v;
    }
  }
}

// ---------------- Stage A: q-shift level (128 -> 256), writes mid[q][b][256][256][16]
// R1 structure: runtime quadrant, sMid LDS round-trip; float4 staging is the only change.
__global__ __launch_bounds__(256) void qshift_kernel(
    const float* __restrict__ w2, const float* __restrict__ loT, float* __restrict__ mid)
{
  __shared__ __align__(16) float sIn[4][12][12][16];   // lo, mixed LH/HL/HH (halo 2)
  __shared__ float sMid[2][12][16][16];                // col-pass intermediates

  const int tid = threadIdx.x;
  const int c = tid & 15;
  const int s = tid >> 4;
  const int tw = blockIdx.x;
  const int th = blockIdx.y;
  const int b  = blockIdx.z & 3;
  const int q  = blockIdx.z >> 2;
  const int m = q >> 1, n = q & 1;
  const int j1 = m ^ n;
  const float sgn = m ? -1.0f : 1.0f;
  const int ih0 = th * 8, iw0 = tw * 8;
  const size_t plane = (size_t)128 * 128 * 16;

  stage_copy<128>(loT + ((size_t)(m * 2 + n) * 4 + b) * plane, &sIn[0][0][0][0], ih0, iw0, tid);
  stage_mix<128>(w2 + ((size_t)((0 * 2 + j1) * 3 + 0) * 4 + b) * plane,
                 w2 + ((size_t)((1 * 2 + (1 ^ j1)) * 3 + 0) * 4 + b) * plane,
                 sgn, &sIn[1][0][0][0], ih0, iw0, tid);
  stage_mix<128>(w2 + ((size_t)((0 * 2 + j1) * 3 + 1) * 4 + b) * plane,
                 w2 + ((size_t)((1 * 2 + (1 ^ j1)) * 3 + 1) * 4 + b) * plane,
                 sgn, &sIn[2][0][0][0], ih0, iw0, tid);
  stage_mix<128>(w2 + ((size_t)((0 * 2 + j1) * 3 + 2) * 4 + b) * plane,
                 w2 + ((size_t)((1 * 2 + (1 ^ j1)) * 3 + 2) * 4 + b) * plane,
                 sgn, &sIn[3][0][0][0], ih0, iw0, tid);
  __syncthreads();

  // Phase B: column pass (along W), tree n filters; thread owns out-col nw=s.
  {
    const int nw = s, pw = nw & 1, qw = nw >> 1;
    float flp[5], fhp[5];
    #pragma unroll
    for (int j = 0; j < 5; ++j) {
      flp[j] = c_DUAL[n][0][9 - (2 * j + pw)];
      fhp[j] = c_DUAL[n][1][9 - (2 * j + pw)];
    }
    #pragma unroll
    for (int r = 0; r < 12; ++r) {
      float lo_v = 0.f, h_v = 0.f;
      #pragma unroll
      for (int j = 0; j < 5; ++j) {
        int x = qw + 4 - j;
        lo_v += flp[j] * sIn[0][r][x][c] + fhp[j] * sIn[1][r][x][c];
        h_v  += flp[j] * sIn[2][r][x][c] + fhp[j] * sIn[3][r][x][c];
      }
      sMid[0][r][nw][c] = lo_v;
      sMid[1][r][nw][c] = h_v;
    }
  }
  __syncthreads();

  // Phase C: row pass (along H), tree m filters; write mid.
  float* outQ = mid + ((size_t)q * 4 + b) * (size_t)(256 * 256 * 16);
  {
    const int nw = s;
    #pragma unroll
    for (int nh = 0; nh < 16; ++nh) {
      int ph = nh & 1, qh = nh >> 1;
      float v = 0.f;
      #pragma unroll
      for (int j = 0; j < 5; ++j) {
        float flp = c_FAR[0][0][0];  // placeholder avoided; real taps below
        (void)flp;
        v += c_DUAL[m][0][9 - (2 * j + ph)] * sMid[0][qh + 4 - j][nw][c]
           + c_DUAL[m][1][9 - (2 * j + ph)] * sMid[1][qh + 4 - j][nw][c];
      }
      outQ[(((size_t)(ih0 * 2 + nh)) * 256 + (size_t)(iw0 * 2 + nw)) * 16 + c] = v;
    }
  }
}

// ---------------- Stage B: Farras level (256 -> 512), sums 4 quadrants, writes out*0.5
// R1 structure: runtime q-loop (#pragma unroll 1), sMid LDS round-trip; float4 staging only change.
__global__ __launch_bounds__(256) void farras_kernel(
    const float* __restrict__ w1, const float* __restrict__ mid, float* __restrict__ out)
{
  __shared__ __align__(16) float sIn[4][12][12][16];
  __shared__ float sMid[2][12][16][16];

  const int tid = threadIdx.x;
  const int c = tid & 15;
  const int s = tid >> 4;
  const int tw = blockIdx.x;
  const int th = blockIdx.y;
  const int b  = blockIdx.z;
  const int ih0 = th * 8, iw0 = tw * 8;
  const size_t plane = (size_t)256 * 256 * 16;

  float acc[16];
  #pragma unroll
  for (int i = 0; i < 16; ++i) acc[i] = 0.f;

  #pragma unroll 1
  for (int q = 0; q < 4; ++q) {
    const int m = q >> 1, n = q & 1;
    const int j1 = m ^ n;
    const float sgn = m ? -1.0f : 1.0f;

    stage_copy<256>(mid + ((size_t)q * 4 + b) * plane, &sIn[0][0][0][0], ih0, iw0, tid);
    stage_mix<256>(w1 + ((size_t)((0 * 2 + j1) * 3 + 0) * 4 + b) * plane,
                   w1 + ((size_t)((1 * 2 + (1 ^ j1)) * 3 + 0) * 4 + b) * plane,
                   sgn, &sIn[1][0][0][0], ih0, iw0, tid);
    stage_mix<256>(w1 + ((size_t)((0 * 2 + j1) * 3 + 1) * 4 + b) * plane,
                   w1 + ((size_t)((1 * 2 + (1 ^ j1)) * 3 + 1) * 4 + b) * plane,
                   sgn, &sIn[2][0][0][0], ih0, iw0, tid);
    stage_mix<256>(w1 + ((size_t)((0 * 2 + j1) * 3 + 2) * 4 + b) * plane,
                   w1 + ((size_t)((1 * 2 + (1 ^ j1)) * 3 + 2) * 4 + b) * plane,
                   sgn, &sIn[3][0][0][0], ih0, iw0, tid);
    __syncthreads();

    // Phase B: column pass, tree n
    {
      const int nw = s, pw = nw & 1, qw = nw >> 1;
      float flp[5], fhp[5];
      #pragma unroll
      for (int j = 0; j < 5; ++j) {
        flp[j] = c_FAR[n][0][9 - (2 * j + pw)];
        fhp[j] = c_FAR[n][1][9 - (2 * j + pw)];
      }
      #pragma unroll
      for (int r = 0; r < 12; ++r) {
        float lo_v = 0.f, h_v = 0.f;
        #pragma unroll
        for (int j = 0; j < 5; ++j) {
          int x = qw + 4 - j;
          lo_v += flp[j] * sIn[0][r][x][c] + fhp[j] * sIn[1][r][x][c];
          h_v  += flp[j] * sIn[2][r][x][c] + fhp[j] * sIn[3][r][x][c];
        }
        sMid[0][r][nw][c] = lo_v;
        sMid[1][r][nw][c] = h_v;
      }
    }
    __syncthreads();

    // Phase C: row pass, tree m; accumulate into registers
    {
      const int nw = s;
      #pragma unroll
      for (int nh = 0; nh < 16; ++nh) {
        int ph = nh & 1, qh = nh >> 1;
        float v = 0.f;
        #pragma unroll
        for (int j = 0; j < 5; ++j) {
          v += c_FAR[m][0][9 - (2 * j + ph)] * sMid[0][qh + 4 - j][nw][c]
             + c_FAR[m][1][9 - (2 * j + ph)] * sMid[1][qh + 4 - j][nw][c];
        }
        acc[nh] += v;
      }
    }
    __syncthreads();  // protect sIn/sMid before next quadrant overwrites
  }

  #pragma unroll
  for (int nh = 0; nh < 16; ++nh) {
    size_t gh = (size_t)(ih0 * 2 + nh);
    size_t gw = (size_t)(iw0 * 2 + s);
    out[(((size_t)b * 512 + gh) * 512 + gw) * 16 + c] = acc[nh] * 0.5f;
  }
}

extern "C" void kernel_launch(void* const* d_in, const int* in_sizes, int n_in,
                              void* d_out, int out_size, void* d_ws, size_t ws_size,
                              hipStream_t stream) {
  const float* w1 = (const float*)d_in[0];   // [2,2,3,4,256,256,16]
  const float* w2 = (const float*)d_in[1];   // [2,2,3,4,128,128,16]
  const float* lo = (const float*)d_in[2];   // [2,2,4,128,128,16]
  float* out = (float*)d_out;                // [4,512,512,16]
  float* mid = (float*)d_ws;                 // [4 quadrants][4][256][256][16] = 64 MiB

  qshift_kernel<<<dim3(16, 16, 16), 256, 0, stream>>>(w2, lo, mid);
  farras_kernel<<<dim3(32, 32, 4), 256, 0, stream>>>(w1, mid, out);
}

// Round 7
// 219.439 us; speedup vs baseline: 9.0550x; 1.2598x over previous
//
#include <hip/hip_runtime.h>

#define INV_SQRT2f 0.70710678118654752440f

// Analysis filters; synthesis filter f[k] = AF[9-k] (time reversal).
// Polyphase synthesis: out[2q+p] = sum_{j=0..4} AF[9-(2j+p)] * x[(q+2-j) mod Nin]
__constant__ float c_FAR[2][2][10] = {
  {{0.0f, -0.08838834764832f, 0.08838834764832f, 0.69587998903400f, 0.69587998903400f,
    0.08838834764832f, -0.08838834764832f, 0.01122679215254f, 0.01122679215254f, 0.0f},
   {0.0f, -0.01122679215254f, 0.01122679215254f, 0.08838834764832f, 0.08838834764832f,
    -0.69587998903400f, 0.69587998903400f, -0.08838834764832f, -0.08838834764832f, 0.0f}},
  {{0.01122679215254f, 0.01122679215254f, -0.08838834764832f, 0.08838834764832f, 0.69587998903400f,
    0.69587998903400f, 0.08838834764832f, -0.08838834764832f, 0.0f, 0.0f},
   {0.0f, 0.0f, -0.08838834764832f, -0.08838834764832f, 0.69587998903400f,
    -0.69587998903400f, 0.08838834764832f, 0.08838834764832f, 0.01122679215254f, -0.01122679215254f}}
};
__constant__ float c_DUAL[2][2][10] = {
  {{0.03516384f, 0.0f, -0.08832942f, 0.23389032f, 0.76027237f,
    0.58751830f, 0.0f, -0.11430184f, 0.0f, 0.0f},
   {0.0f, 0.0f, -0.11430184f, 0.0f, 0.58751830f,
    -0.76027237f, 0.23389032f, 0.08832942f, 0.0f, -0.03516384f}},
  {{0.0f, 0.0f, -0.11430184f, 0.0f, 0.58751830f,
    0.76027237f, 0.23389032f, -0.08832942f, 0.0f, 0.03516384f},
   {-0.03516384f, 0.0f, 0.08832942f, 0.23389032f, -0.76027237f,
    0.58751830f, 0.0f, -0.11430184f, 0.0f, 0.0f}}
};

// ---- staging: 12x12 spatial halo tile x 16 ch = 576 float4, 256 threads ----
template<int NSZ>
__device__ __forceinline__ void stage_copy(const float* __restrict__ src, float* __restrict__ dst,
                                           int ih0, int iw0, int tid) {
  #pragma unroll
  for (int it = 0; it < 3; ++it) {
    int e = tid + (it << 8);
    if (it < 2 || e < 576) {
      int r = e / 48;
      int cc = e - r * 48;
      int gr = (ih0 + r - 2) & (NSZ - 1);
      int gc = (iw0 + (cc >> 2) - 2) & (NSZ - 1);
      float4 v = *reinterpret_cast<const float4*>(src + (((size_t)gr * NSZ + gc) << 4) + ((cc & 3) << 2));
      *reinterpret_cast<float4*>(dst + (e << 2)) = v;
    }
  }
}

template<int NSZ>
__device__ __forceinline__ void stage_mix(const float* __restrict__ A, const float* __restrict__ B,
                                          float sgn, float* __restrict__ dst,
                                          int ih0, int iw0, int tid) {
  #pragma unroll
  for (int it = 0; it < 3; ++it) {
    int e = tid + (it << 8);
    if (it < 2 || e < 576) {
      int r = e / 48;
      int cc = e - r * 48;
      int gr = (ih0 + r - 2) & (NSZ - 1);
      int gc = (iw0 + (cc >> 2) - 2) & (NSZ - 1);
      size_t off = (((size_t)gr * NSZ + gc) << 4) + ((cc & 3) << 2);
      float4 a = *reinterpret_cast<const float4*>(A + off);
      float4 b = *reinterpret_cast<const float4*>(B + off);
      float4 v;
      v.x = (a.x + sgn * b.x) * INV_SQRT2f;
      v.y = (a.y + sgn * b.y) * INV_SQRT2f;
      v.z = (a.z + sgn * b.z) * INV_SQRT2f;
      v.w = (a.w + sgn * b.w) * INV_SQRT2f;
      *reinterpret_cast<float4*>(dst + (e << 2)) = v;
    }
  }
}

// ---------------- Stage A: q-shift level (128 -> 256), writes mid[q][b][256][256][16]
// Runtime quadrant (body emitted once); col pass LDS->regs; row pass register-gather.
// LDS = sIn only (36.9 KB) -> 4 blocks/CU.
__global__ __launch_bounds__(256) void qshift_kernel(
    const float* __restrict__ w2, const float* __restrict__ loT, float* __restrict__ mid)
{
  __shared__ __align__(16) float sIn[4][12][12][16];   // lo, mixed LH/HL/HH (halo 2)

  const int tid = threadIdx.x;
  const int c = tid & 15;
  const int s = tid >> 4;
  const int tw = blockIdx.x;
  const int th = blockIdx.y;
  const int b  = blockIdx.z & 3;
  const int q  = blockIdx.z >> 2;
  const int m = q >> 1, n = q & 1;
  const int j1 = m ^ n;
  const float sgn = m ? -1.0f : 1.0f;
  const int ih0 = th * 8, iw0 = tw * 8;
  const size_t plane = (size_t)128 * 128 * 16;

  stage_copy<128>(loT + ((size_t)(m * 2 + n) * 4 + b) * plane, &sIn[0][0][0][0], ih0, iw0, tid);
  stage_mix<128>(w2 + ((size_t)((0 * 2 + j1) * 3 + 0) * 4 + b) * plane,
                 w2 + ((size_t)((1 * 2 + (1 ^ j1)) * 3 + 0) * 4 + b) * plane,
                 sgn, &sIn[1][0][0][0], ih0, iw0, tid);
  stage_mix<128>(w2 + ((size_t)((0 * 2 + j1) * 3 + 1) * 4 + b) * plane,
                 w2 + ((size_t)((1 * 2 + (1 ^ j1)) * 3 + 1) * 4 + b) * plane,
                 sgn, &sIn[2][0][0][0], ih0, iw0, tid);
  stage_mix<128>(w2 + ((size_t)((0 * 2 + j1) * 3 + 2) * 4 + b) * plane,
                 w2 + ((size_t)((1 * 2 + (1 ^ j1)) * 3 + 2) * 4 + b) * plane,
                 sgn, &sIn[3][0][0][0], ih0, iw0, tid);
  __syncthreads();

  // Column pass (along W), tree n filters; thread owns out-col nw=s, channel c.
  const int pw = s & 1, qw = s >> 1;
  float flp[5], fhp[5];
  #pragma unroll
  for (int j = 0; j < 5; ++j) {
    flp[j] = c_DUAL[n][0][9 - (2 * j + pw)];
    fhp[j] = c_DUAL[n][1][9 - (2 * j + pw)];
  }
  float lo2[12], h2[12];
  #pragma unroll
  for (int r = 0; r < 12; ++r) {
    float lo_v = 0.f, h_v = 0.f;
    #pragma unroll
    for (int j = 0; j < 5; ++j) {
      int x = qw + 4 - j;
      lo_v += flp[j] * sIn[0][r][x][c] + fhp[j] * sIn[1][r][x][c];
      h_v  += flp[j] * sIn[2][r][x][c] + fhp[j] * sIn[3][r][x][c];
    }
    lo2[r] = lo_v;
    h2[r] = h_v;
  }

  // Row pass (along H), tree m filters, register gather; write mid.
  float* outQ = mid + ((size_t)q * 4 + b) * (size_t)(256 * 256 * 16);
  #pragma unroll
  for (int nh = 0; nh < 16; ++nh) {
    int ph = nh & 1, qh = nh >> 1;
    float v = 0.f;
    #pragma unroll
    for (int j = 0; j < 5; ++j) {
      v += c_DUAL[m][0][9 - (2 * j + ph)] * lo2[qh + 4 - j]
         + c_DUAL[m][1][9 - (2 * j + ph)] * h2[qh + 4 - j];
    }
    outQ[(((size_t)(ih0 * 2 + nh)) * 256 + (size_t)(iw0 * 2 + s)) * 16 + c] = v;
  }
}

// ---------------- Stage B: Farras level (256 -> 512), sums 4 quadrants, writes out*0.5
// Runtime q-loop (#pragma unroll 1, body emitted once); register row pass; no sMid.
__global__ __launch_bounds__(256) void farras_kernel(
    const float* __restrict__ w1, const float* __restrict__ mid, float* __restrict__ out)
{
  __shared__ __align__(16) float sIn[4][12][12][16];

  const int tid = threadIdx.x;
  const int c = tid & 15;
  const int s = tid >> 4;
  const int tw = blockIdx.x;
  const int th = blockIdx.y;
  const int b  = blockIdx.z;
  const int ih0 = th * 8, iw0 = tw * 8;
  const size_t plane = (size_t)256 * 256 * 16;

  float acc[16];
  #pragma unroll
  for (int i = 0; i < 16; ++i) acc[i] = 0.f;

  const int pw = s & 1, qw = s >> 1;

  #pragma unroll 1
  for (int q = 0; q < 4; ++q) {
    const int m = q >> 1, n = q & 1;
    const int j1 = m ^ n;
    const float sgn = m ? -1.0f : 1.0f;

    stage_copy<256>(mid + ((size_t)q * 4 + b) * plane, &sIn[0][0][0][0], ih0, iw0, tid);
    stage_mix<256>(w1 + ((size_t)((0 * 2 + j1) * 3 + 0) * 4 + b) * plane,
                   w1 + ((size_t)((1 * 2 + (1 ^ j1)) * 3 + 0) * 4 + b) * plane,
                   sgn, &sIn[1][0][0][0], ih0, iw0, tid);
    stage_mix<256>(w1 + ((size_t)((0 * 2 + j1) * 3 + 1) * 4 + b) * plane,
                   w1 + ((size_t)((1 * 2 + (1 ^ j1)) * 3 + 1) * 4 + b) * plane,
                   sgn, &sIn[2][0][0][0], ih0, iw0, tid);
    stage_mix<256>(w1 + ((size_t)((0 * 2 + j1) * 3 + 2) * 4 + b) * plane,
                   w1 + ((size_t)((1 * 2 + (1 ^ j1)) * 3 + 2) * 4 + b) * plane,
                   sgn, &sIn[3][0][0][0], ih0, iw0, tid);
    __syncthreads();

    // Column pass, tree n filters
    float flp[5], fhp[5];
    #pragma unroll
    for (int j = 0; j < 5; ++j) {
      flp[j] = c_FAR[n][0][9 - (2 * j + pw)];
      fhp[j] = c_FAR[n][1][9 - (2 * j + pw)];
    }
    float lo2[12], h2[12];
    #pragma unroll
    for (int r = 0; r < 12; ++r) {
      float lo_v = 0.f, h_v = 0.f;
      #pragma unroll
      for (int j = 0; j < 5; ++j) {
        int x = qw + 4 - j;
        lo_v += flp[j] * sIn[0][r][x][c] + fhp[j] * sIn[1][r][x][c];
        h_v  += flp[j] * sIn[2][r][x][c] + fhp[j] * sIn[3][r][x][c];
      }
      lo2[r] = lo_v;
      h2[r] = h_v;
    }
    __syncthreads();  // sIn fully consumed; next iteration may overwrite

    // Row pass, tree m filters; register gather -> accumulate
    #pragma unroll
    for (int nh = 0; nh < 16; ++nh) {
      int ph = nh & 1, qh = nh >> 1;
      float v = 0.f;
      #pragma unroll
      for (int j = 0; j < 5; ++j) {
        v += c_FAR[m][0][9 - (2 * j + ph)] * lo2[qh + 4 - j]
           + c_FAR[m][1][9 - (2 * j + ph)] * h2[qh + 4 - j];
      }
      acc[nh] += v;
    }
  }

  #pragma unroll
  for (int nh = 0; nh < 16; ++nh) {
    size_t gh = (size_t)(ih0 * 2 + nh);
    size_t gw = (size_t)(iw0 * 2 + s);
    out[(((size_t)b * 512 + gh) * 512 + gw) * 16 + c] = acc[nh] * 0.5f;
  }
}

extern "C" void kernel_launch(void* const* d_in, const int* in_sizes, int n_in,
                              void* d_out, int out_size, void* d_ws, size_t ws_size,
                              hipStream_t stream) {
  const float* w1 = (const float*)d_in[0];   // [2,2,3,4,256,256,16]
  const float* w2 = (const float*)d_in[1];   // [2,2,3,4,128,128,16]
  const float* lo = (const float*)d_in[2];   // [2,2,4,128,128,16]
  float* out = (float*)d_out;                // [4,512,512,16]
  float* mid = (float*)d_ws;                 // [4 quadrants][4][256][256][16] = 64 MiB

  qshift_kernel<<<dim3(16, 16, 16), 256, 0, stream>>>(w2, lo, mid);
  farras_kernel<<<dim3(32, 32, 4), 256, 0, stream>>>(w1, mid, out);
}